// Round 13
// baseline (1879.270 us; speedup 1.0000x reference)
//
#include <hip/hip_runtime.h>

#define D_DIM 1024
#define B_ROWS 65536

typedef unsigned short u16;
typedef __attribute__((ext_vector_type(8))) __bf16 bf16x8;
typedef __attribute__((ext_vector_type(4))) float f32x4;
typedef __attribute__((ext_vector_type(8))) unsigned short u16x8;

__device__ __forceinline__ u16 f2bf(float f) {
  union { float fv; unsigned int i; } v; v.fv = f;
  return (u16)((v.i + 0x7FFFu + ((v.i >> 16) & 1u)) >> 16);
}

// ---------------------------------------------------------------------------
// PK format (kt-major packed bf16), RT = rows/16:
//   granule(row, col) = ((col>>5)*RT + (row>>4))*64 + ((col>>3)&3)*16 + (row&15)
//   u16 offset = granule*8 + (col&7)   (granule = 1 row x 8 cols, 16 B)
// A wave reading granules [g0..g0+64) at lane*16B is one contiguous 1 KB
// coalesced read == exactly one MFMA fragment set (A or B operand).
// ---------------------------------------------------------------------------

struct ZArgs { const u16* Ap[4]; const u16* Wp[4]; u16* opk[4]; };

// Fused stage: y = A_pk @ W_pk^T + cb (+R f32 row-major); optional LN; outputs
// f32 row-major and/or PK bf16.
// Block = 32 rows x 1024 cols, 256 threads (4 waves, wave owns 256 cols).
// BOTH operands stream global->register (PK fragments); ZERO LDS / barriers in
// the K-loop; LDS (34 KB) only for the epilogue. 2 blocks/CU co-resident.
template <int RES, int LN, int OF32, int OPK>
__global__ __launch_bounds__(256, 2) void fused_stage(
    ZArgs Z, const float* __restrict__ cb, const float* __restrict__ Rf,
    const float* __restrict__ lng, const float* __restrict__ lnb,
    float* __restrict__ of32, int RTA, int RTO)
{
  __shared__ __align__(16) float smem[8576];   // ybuf 32x260 | stats 32x4x2
  float* ybuf = smem;
  float* sstats = smem + 8320;

  const int z = blockIdx.y;
  const u16* __restrict__ Ap = Z.Ap[z];
  const u16* __restrict__ Wp = Z.Wp[z];
  u16* __restrict__ opk = Z.opk[z];

  const int slab = blockIdx.x;        // 32-row slab
  const int tid = threadIdx.x;
  const int w = tid >> 6;             // wave 0..3 owns cols [w*256, +256)
  const int lane = tid & 63;
  const int fr = lane & 15;
  const int l4 = lane >> 4;

  f32x4 acc[2][16] = {};

  // ---- K loop: no LDS, no barriers; 18 reg-loads + 32 MFMA per iter ----
  const u16* abase = Ap + (((size_t)slab * 2) * 64 + lane) * 8;
  const u16* wbase = Wp + (((size_t)w * 16) * 64 + lane) * 8;
#pragma unroll 2
  for (int kt = 0; kt < 32; ++kt) {
    bf16x8 af0 = *(const bf16x8*)(abase + ((size_t)kt * RTA) * 512);
    bf16x8 af1 = *(const bf16x8*)(abase + ((size_t)kt * RTA + 1) * 512);
    bf16x8 wf[16];
#pragma unroll
    for (int lt = 0; lt < 16; ++lt)
      wf[lt] = *(const bf16x8*)(wbase + ((size_t)kt * 64 + lt) * 512);
    __builtin_amdgcn_s_setprio(1);
#pragma unroll
    for (int lt = 0; lt < 16; ++lt) {
      acc[0][lt] = __builtin_amdgcn_mfma_f32_16x16x32_bf16(af0, wf[lt], acc[0][lt], 0, 0, 0);
      acc[1][lt] = __builtin_amdgcn_mfma_f32_16x16x32_bf16(af1, wf[lt], acc[1][lt], 0, 0, 0);
    }
    __builtin_amdgcn_s_setprio(0);
  }

  // ---- epilogue ----
  if (cb) {
#pragma unroll
    for (int lt = 0; lt < 16; ++lt) {
      const float c = cb[w * 256 + lt * 16 + fr];
#pragma unroll
      for (int rt = 0; rt < 2; ++rt)
#pragma unroll
        for (int j = 0; j < 4; ++j) acc[rt][lt][j] += c;
    }
  }

  if (RES) {
#pragma unroll
    for (int rt = 0; rt < 2; ++rt)
#pragma unroll
      for (int j = 0; j < 4; ++j) {
        const float* rp = Rf + (size_t)(slab * 32 + rt * 16 + l4 * 4 + j) * D_DIM
                          + w * 256 + fr;
#pragma unroll
        for (int lt = 0; lt < 16; ++lt) acc[rt][lt][j] += rp[lt * 16];
      }
  }

  if (LN) {
#pragma unroll
    for (int rt = 0; rt < 2; ++rt)
#pragma unroll
      for (int j = 0; j < 4; ++j) {
        float s = 0.f, ss = 0.f;
#pragma unroll
        for (int lt = 0; lt < 16; ++lt) { float v = acc[rt][lt][j]; s += v; ss += v * v; }
        s += __shfl_xor(s, 1, 64);  ss += __shfl_xor(ss, 1, 64);
        s += __shfl_xor(s, 2, 64);  ss += __shfl_xor(ss, 2, 64);
        s += __shfl_xor(s, 4, 64);  ss += __shfl_xor(ss, 4, 64);
        s += __shfl_xor(s, 8, 64);  ss += __shfl_xor(ss, 8, 64);
        if (fr == 0) {
          const int row = rt * 16 + l4 * 4 + j;
          sstats[(row * 4 + w) * 2] = s;
          sstats[(row * 4 + w) * 2 + 1] = ss;
        }
      }
    __syncthreads();
#pragma unroll
    for (int rt = 0; rt < 2; ++rt)
#pragma unroll
      for (int j = 0; j < 4; ++j) {
        const int row = rt * 16 + l4 * 4 + j;
        float S = 0.f, SS = 0.f;
#pragma unroll
        for (int ww = 0; ww < 4; ++ww) {
          S += sstats[(row * 4 + ww) * 2];
          SS += sstats[(row * 4 + ww) * 2 + 1];
        }
        const float mean = S * (1.f / 1024.f);
        const float var = SS * (1.f / 1024.f) - mean * mean;
        const float rstd = rsqrtf(var + 1e-5f);
#pragma unroll
        for (int lt = 0; lt < 16; ++lt)
          acc[rt][lt][j] = (acc[rt][lt][j] - mean) * rstd;
      }
#pragma unroll
    for (int lt = 0; lt < 16; ++lt) {
      const float gv = lng[w * 256 + lt * 16 + fr];
      const float bv = lnb[w * 256 + lt * 16 + fr];
#pragma unroll
      for (int rt = 0; rt < 2; ++rt)
#pragma unroll
        for (int j = 0; j < 4; ++j)
          acc[rt][lt][j] = acc[rt][lt][j] * gv + bv;
    }
  }
  __syncthreads();

  // output phases: phase p = cols [p*256, +256) (wave p's slice)
#pragma unroll
  for (int p = 0; p < 4; ++p) {
    if (w == p) {
#pragma unroll
      for (int rt = 0; rt < 2; ++rt)
#pragma unroll
        for (int j = 0; j < 4; ++j) {
          float* yb = ybuf + (size_t)(rt * 16 + l4 * 4 + j) * 260 + fr;
#pragma unroll
          for (int lt = 0; lt < 16; ++lt) yb[lt * 16] = acc[rt][lt][j];
        }
    }
    __syncthreads();
    if (OF32) {
      const int row = tid >> 3, cseg = (tid & 7) * 32;
      float* op = of32 + (size_t)(slab * 32 + row) * D_DIM + p * 256 + cseg;
      const float* yb = ybuf + (size_t)row * 260 + cseg;
#pragma unroll
      for (int i = 0; i < 8; ++i) *(f32x4*)(op + i * 4) = *(const f32x4*)(yb + i * 4);
    }
    if (OPK) {
#pragma unroll
      for (int i = 0; i < 4; ++i) {
        const int gid = i * 256 + tid;
        const int ktl = gid >> 7, rem = gid & 127;
        const int rt = rem >> 6, g = (rem >> 4) & 3, fr2 = rem & 15;
        const float* yb = ybuf + (size_t)(rt * 16 + fr2) * 260 + ktl * 32 + g * 8;
        f32x4 y0 = *(const f32x4*)yb;
        f32x4 y1 = *(const f32x4*)(yb + 4);
        u16x8 o;
#pragma unroll
        for (int t = 0; t < 4; ++t) { o[t] = f2bf(y0[t]); o[t + 4] = f2bf(y1[t]); }
        const size_t gran = ((size_t)(p * 8 + ktl) * RTO + slab * 2 + rt) * 64 + g * 16 + fr2;
        *(u16x8*)&opk[gran * 8] = o;
      }
    }
    __syncthreads();
  }
}

// ---------------- f32 row-major -> PK bf16 (block = 128-row slab) ----------
__global__ __launch_bounds__(256) void pack_pk(const float* __restrict__ src,
                                               u16* __restrict__ dst, int RT)
{
  const int base_row = blockIdx.x * 128;
#pragma unroll 4
  for (int i = 0; i < 64; ++i) {
    const int idx = i * 256 + threadIdx.x;
    const int row = base_row + (idx >> 7);
    const int c8 = idx & 127;
    const float* sp = src + (size_t)row * D_DIM + c8 * 8;
    f32x4 a = *(const f32x4*)sp;
    f32x4 b = *(const f32x4*)(sp + 4);
    u16x8 o;
#pragma unroll
    for (int t = 0; t < 4; ++t) { o[t] = f2bf(a[t]); o[t + 4] = f2bf(b[t]); }
    const size_t gran = ((size_t)(c8 >> 2) * RT + (row >> 4)) * 64 + (c8 & 3) * 16 + (row & 15);
    *(u16x8*)&dst[gran * 8] = o;
  }
}

struct TP4 { const float* s[4]; u16* d[4]; };

// wv (f32 row-major) -> wv^T as PK bf16 (RT=64), batched z=0..3
__global__ __launch_bounds__(256) void transpose_pack(TP4 p) {
  __shared__ float tile[32][33];
  const int z = blockIdx.z;
  const float* src = p.s[z];
  u16* dst = p.d[z];
  const int tx = threadIdx.x & 31, ty = threadIdx.x >> 5;
  const int gx = blockIdx.x * 32, gy = blockIdx.y * 32;
#pragma unroll
  for (int i = 0; i < 4; ++i) {
    const int r = ty + i * 8;
    tile[r][tx] = src[(size_t)(gy + r) * D_DIM + gx + tx];
  }
  __syncthreads();
#pragma unroll
  for (int i = 0; i < 4; ++i) {
    const int drow = gx + ty + i * 8;
    const int dcol = gy + tx;
    const size_t gran = ((size_t)(dcol >> 5) * 64 + (drow >> 4)) * 64
                        + ((dcol >> 3) & 3) * 16 + (drow & 15);
    dst[gran * 8 + (dcol & 7)] = f2bf(tile[tx][ty + i * 8]);
  }
}

struct BiasArgs { const float* wout[4]; const float* bin[4]; const float* bout[4]; };

__global__ __launch_bounds__(256) void bias_kernel(BiasArgs p, float* cb) {
  const int z = blockIdx.z;
  const int i = blockIdx.x * 256 + threadIdx.x;
  const float* wrow = p.wout[z] + (size_t)i * D_DIM;
  const float* bv = p.bin[z] + 2 * D_DIM;
  float s = 0.f;
  for (int j = 0; j < D_DIM; j += 4) {
    f32x4 w4 = *(const f32x4*)&wrow[j];
    f32x4 b4 = *(const f32x4*)&bv[j];
#pragma unroll
    for (int t = 0; t < 4; ++t) s += w4[t] * b4[t];
  }
  cb[(size_t)z * D_DIM + i] = s + p.bout[z][i];
}

extern "C" void kernel_launch(void* const* d_in, const int* in_sizes, int n_in,
                              void* d_out, int out_size, void* d_ws, size_t ws_size,
                              hipStream_t stream) {
  (void)in_sizes; (void)n_in; (void)out_size; (void)ws_size;
  const size_t BD = (size_t)B_ROWS * D_DIM;
  const size_t DD = (size_t)D_DIM * D_DIM;

  const float* feat_local = (const float*)d_in[0];
  const float* feat_tact  = (const float*)d_in[1];
  const float* feat_strat = (const float*)d_in[2];
  const float* w_in[4]  = {(const float*)d_in[3],  (const float*)d_in[7],  (const float*)d_in[11], (const float*)d_in[15]};
  const float* b_in[4]  = {(const float*)d_in[4],  (const float*)d_in[8],  (const float*)d_in[12], (const float*)d_in[16]};
  const float* w_out[4] = {(const float*)d_in[5],  (const float*)d_in[9],  (const float*)d_in[13], (const float*)d_in[17]};
  const float* b_out[4] = {(const float*)d_in[6],  (const float*)d_in[10], (const float*)d_in[14], (const float*)d_in[18]};
  const float* ln_g[3] = {(const float*)d_in[19], (const float*)d_in[21], (const float*)d_in[23]};
  const float* ln_b[3] = {(const float*)d_in[20], (const float*)d_in[22], (const float*)d_in[24]};

  u16* buf0 = (u16*)d_ws;              // PK bf16 stream buffers (128 MB each)
  u16* buf1 = buf0 + BD;
  float* tacF = (float*)(buf1 + BD);   // tacA f32 row-major (256 MB)
  u16* wvT  = (u16*)(tacF + BD);       // 4*DD PK
  u16* wobf = wvT + 4 * DD;            // 4*DD PK
  u16* Wc   = wobf + 4 * DD;           // 4*DD PK
  float* cb = (float*)(Wc + 4 * DD);

  float* out = (float*)d_out;
  float* o_loc = out;
  float* o_tac = out + BD;
  float* o_str = out + 2 * BD;

  // 0. pack: local f32 -> PK (buf0); w_out -> PK
  hipLaunchKernelGGL(pack_pk, dim3(512), dim3(256), 0, stream, feat_local, buf0, 4096);
  for (int z = 0; z < 4; ++z)
    hipLaunchKernelGGL(pack_pk, dim3(8), dim3(256), 0, stream, w_out[z], wobf + z * DD, 64);

  // 1. wvT_z = (w_in_z[2D:,:])^T as PK
  TP4 tp;
  for (int z = 0; z < 4; ++z) { tp.s[z] = w_in[z] + 2 * DD; tp.d[z] = wvT + z * DD; }
  hipLaunchKernelGGL(transpose_pack, dim3(32, 32, 4), dim3(256), 0, stream, tp);

  // 2. combined bias c = w_out*bv + b_out (f32)
  BiasArgs ba;
  for (int z = 0; z < 4; ++z) { ba.wout[z] = w_out[z]; ba.bin[z] = b_in[z]; ba.bout[z] = b_out[z]; }
  hipLaunchKernelGGL(bias_kernel, dim3(4, 1, 4), dim3(256), 0, stream, ba, cb);

  // 3. Wc_z = wobf_z @ wvT_z^T -> PK (one batched launch, 32x4 blocks)
  ZArgs zw;
  for (int z = 0; z < 4; ++z) { zw.Ap[z] = wobf + z * DD; zw.Wp[z] = wvT + z * DD; zw.opk[z] = Wc + z * DD; }
  hipLaunchKernelGGL((fused_stage<0, 0, 0, 1>), dim3(32, 4), dim3(256), 0, stream,
                     zw, (const float*)nullptr, (const float*)nullptr,
                     (const float*)nullptr, (const float*)nullptr,
                     (float*)nullptr, 64, 64);

  auto mk = [](const u16* a, const u16* w, u16* o) {
    ZArgs zz;
    for (int z = 0; z < 4; ++z) { zz.Ap[z] = a; zz.Wp[z] = w; zz.opk[z] = o; }
    return zz;
  };

  // 4. S1: tacA = LN1(local@Wc0 + c0 + tact) -> tacF f32 + buf1 PK
  hipLaunchKernelGGL((fused_stage<1, 1, 1, 1>), dim3(2048), dim3(256), 0, stream,
                     mk(buf0, Wc + 0 * DD, buf1), cb + 0, feat_tact,
                     ln_g[0], ln_b[0], tacF, 4096, 4096);

  // 5. S2: strat = LN2(tacA@Wc1 + c1 + strat_in) -> o_str f32 + buf0 PK
  hipLaunchKernelGGL((fused_stage<1, 1, 1, 1>), dim3(2048), dim3(256), 0, stream,
                     mk(buf1, Wc + 1 * DD, buf0), cb + 1024, feat_strat,
                     ln_g[1], ln_b[1], o_str, 4096, 4096);

  // 6. S3: tacB = LN3(strat@Wc2 + c2 + tacA_f32) -> o_tac f32 + buf1 PK
  hipLaunchKernelGGL((fused_stage<1, 1, 1, 1>), dim3(2048), dim3(256), 0, stream,
                     mk(buf0, Wc + 2 * DD, buf1), cb + 2048, tacF,
                     ln_g[2], ln_b[2], o_tac, 4096, 4096);

  // 7. S4: loc = local + tacB@Wc3 + c3 -> o_loc f32 (no LN, no PK)
  hipLaunchKernelGGL((fused_stage<1, 0, 1, 0>), dim3(2048), dim3(256), 0, stream,
                     mk(buf1, Wc + 3 * DD, (u16*)nullptr), cb + 3072, feat_local,
                     (const float*)nullptr, (const float*)nullptr, o_loc, 4096, 4096);
}

// Round 14
// 1482.217 us; speedup vs baseline: 1.2679x; 1.2679x over previous
//
#include <hip/hip_runtime.h>

#define D_DIM 1024
#define B_ROWS 65536
#define NKT 16                 // K tiles of 64 (K = 1024 everywhere)
#define TILE_U16 8192          // 128 rows x 64 cols bf16

typedef unsigned short u16;
typedef __attribute__((ext_vector_type(8))) __bf16 bf16x8;
typedef __attribute__((ext_vector_type(4))) float f32x4;
typedef __attribute__((ext_vector_type(8))) unsigned short u16x8;

typedef const __attribute__((address_space(1))) void* gas_cptr;
typedef __attribute__((address_space(3))) void* las_ptr;

__device__ __forceinline__ u16 f2bf(float f) {
  union { float fv; unsigned int i; } v; v.fv = f;
  return (u16)((v.i + 0x7FFFu + ((v.i >> 16) & 1u)) >> 16);
}
__device__ __forceinline__ float bf2f(u16 u) {
  union { unsigned int i; float f; } v; v.i = ((unsigned int)u) << 16; return v.f;
}

// ---------------------------------------------------------------------------
// PK layout (tile-major): P(t,kt,r,g) = ((t*NKT+kt)*128 + r)*64 + g*8 (u16),
// where t=row>>7, r=row&127, kt=col>>6; stored granule g holds source cols
// kt*64 + (g^(r&7))*8 .. +8  (XOR bank swizzle baked in).
// Each (t,kt) chunk = 16 KB contiguous -> perfect HBM streams.
// ---------------------------------------------------------------------------

// ---------------- GEMM: C = A_pk @ W_pk^T (+bias) (+R f32) ------------------
// 128x128 tile, BK=64, 4 waves, glds of CONTIGUOUS 16 KB packed tiles,
// LDS-staged coalesced epilogue. (R9-proven structure.)
template <int RESID, int OUTM>   // RESID: 0 none, 1 f32 row-major ; OUTM: 1 f32, 2 PK
__global__ __launch_bounds__(256, 4) void gemm_pk(
    const u16* __restrict__ Ap, const u16* __restrict__ Wp,
    const float* __restrict__ bias, const float* __restrict__ Rf, void* Op)
{
  __shared__ __align__(16) u16 smem[2 * TILE_U16];   // 32 KB: sA | sB, reused as eC
  u16* sA = smem;
  u16* sB = smem + TILE_U16;

  const int bm = blockIdx.y, bn = blockIdx.x;
  const int tid = threadIdx.x;
  const int wave = tid >> 6;
  const int lane = tid & 63;
  const int wm = wave >> 1, wn = wave & 1;
  const int fr = lane & 15;
  const int l4 = lane >> 4;

  const u16* Abase = Ap + (size_t)bm * NKT * TILE_U16;
  const u16* Wbase = Wp + (size_t)bn * NKT * TILE_U16;

  f32x4 acc[4][4] = {};

  for (int kt = 0; kt < NKT; ++kt) {
    const u16* at = Abase + kt * TILE_U16;
    const u16* wt = Wbase + kt * TILE_U16;
#pragma unroll
    for (int i = 0; i < 4; ++i) {
      __builtin_amdgcn_global_load_lds((gas_cptr)(at + (i * 256 + tid) * 8),
                                       (las_ptr)(sA + (i * 256 + tid) * 8), 16, 0, 0);
      __builtin_amdgcn_global_load_lds((gas_cptr)(wt + (i * 256 + tid) * 8),
                                       (las_ptr)(sB + (i * 256 + tid) * 8), 16, 0, 0);
    }
    __syncthreads();
#pragma unroll
    for (int ks = 0; ks < 2; ++ks) {
      bf16x8 af[4], bf[4];
#pragma unroll
      for (int m = 0; m < 4; ++m) {
        const int row = wm * 64 + m * 16 + fr;
        af[m] = *(const bf16x8*)&sA[row * 64 + (((ks * 4 + l4) ^ (row & 7)) * 8)];
      }
#pragma unroll
      for (int n = 0; n < 4; ++n) {
        const int row = wn * 64 + n * 16 + fr;
        bf[n] = *(const bf16x8*)&sB[row * 64 + (((ks * 4 + l4) ^ (row & 7)) * 8)];
      }
#pragma unroll
      for (int m = 0; m < 4; ++m)
#pragma unroll
        for (int n = 0; n < 4; ++n)
          acc[m][n] = __builtin_amdgcn_mfma_f32_16x16x32_bf16(af[m], bf[n], acc[m][n], 0, 0, 0);
    }
    __syncthreads();
  }

  // -------- LDS-staged epilogue: two half-tiles of 64 rows --------
  float* eC = (float*)smem;            // 64 x 128 f32 = 32 KB, c4-XOR anti-bank
  const int q4 = l4 * 4;
#pragma unroll
  for (int H = 0; H < 2; ++H) {
    if (wm == H) {
#pragma unroll
      for (int m = 0; m < 4; ++m)
#pragma unroll
        for (int j = 0; j < 4; ++j) {
          const int r = m * 16 + q4 + j;
#pragma unroll
          for (int n = 0; n < 4; ++n) {
            const int c = wn * 64 + n * 16 + fr;
            const int c4 = c >> 2;
            eC[r * 128 + ((c4 ^ ((r >> 2) & 7)) * 4) + (c & 3)] = acc[m][n][j];
          }
        }
    }
    __syncthreads();
#pragma unroll
    for (int it = 0; it < 4; ++it) {
      const int idx = it * 256 + tid;
      const int r = idx >> 4;          // 0..63
      const int g8 = idx & 15;         // 8-col group within 128
      const int gr = bm * 128 + H * 64 + r;
      const int c4a = g8 * 2, c4b = g8 * 2 + 1;
      const int rx = (r >> 2) & 7;
      f32x4 c0 = *(const f32x4*)&eC[r * 128 + ((c4a ^ rx) * 4)];
      f32x4 c1 = *(const f32x4*)&eC[r * 128 + ((c4b ^ rx) * 4)];
      const int gc0 = bn * 128 + g8 * 8;
      if (bias) {
        f32x4 b0 = *(const f32x4*)&bias[gc0];
        f32x4 b1 = *(const f32x4*)&bias[gc0 + 4];
#pragma unroll
        for (int t = 0; t < 4; ++t) { c0[t] += b0[t]; c1[t] += b1[t]; }
      }
      if (RESID == 1) {
        const float* rp = Rf + (size_t)gr * D_DIM + gc0;
        f32x4 r0 = *(const f32x4*)rp;
        f32x4 r1 = *(const f32x4*)(rp + 4);
#pragma unroll
        for (int t = 0; t < 4; ++t) { c0[t] += r0[t]; c1[t] += r1[t]; }
      }
      if (OUTM == 1) {
        float* op = (float*)Op + (size_t)gr * D_DIM + gc0;
        *(f32x4*)op = c0;
        *(f32x4*)(op + 4) = c1;
      } else {
        const int t_r = gr >> 7, rr = gr & 127;
        const int kt = gc0 >> 6, gs = (gc0 & 63) >> 3;
        const size_t P = ((size_t)(t_r * NKT + kt) * 128 + rr) * 64 + ((gs ^ (rr & 7)) * 8);
        u16x8 ov;
#pragma unroll
        for (int t = 0; t < 4; ++t) { ov[t] = f2bf(c0[t]); ov[t + 4] = f2bf(c1[t]); }
        *(u16x8*)&((u16*)Op)[P] = ov;
      }
    }
    __syncthreads();
  }
}

// ---------------- LayerNorm over PK: z = y_pk + R(f32); LN; outputs --------
// Thread = one granule column: holds 128 cols of ONE row (z[16][8], static).
// All y/PK accesses are 4 KB contiguous chunks; R/f32 are 256B per 8 lanes.
// Row reduce = 3 shfl_xor (8 threads per row, wave-local). No LDS.
template <int OF32, int OPK>
__global__ __launch_bounds__(256, 2) void ln_pk(
    const u16* __restrict__ Yp, const float* __restrict__ Rf,
    const float* __restrict__ lng, const float* __restrict__ lnb,
    float* __restrict__ of32, u16* __restrict__ opk)
{
  const int tile = blockIdx.x;                     // 128-row tile
  const int gidx = blockIdx.y * 256 + threadIdx.x; // granule within chunk (0..1023)
  const int r = gidx >> 3;                         // row within tile
  const int g = gidx & 7;
  const int gc = g ^ (r & 7);                      // logical col-group
  const size_t grow = (size_t)tile * 128 + r;

  float z[16][8];
  float s = 0.f, ss = 0.f;
#pragma unroll
  for (int kt = 0; kt < 16; ++kt) {
    u16x8 v = *(const u16x8*)&Yp[((size_t)(tile * NKT + kt) * 128) * 64 + (size_t)gidx * 8];
    const float* rp = Rf + grow * D_DIM + kt * 64 + gc * 8;
    f32x4 r0 = *(const f32x4*)rp;
    f32x4 r1 = *(const f32x4*)(rp + 4);
#pragma unroll
    for (int e = 0; e < 4; ++e) {
      z[kt][e] = bf2f(v[e]) + r0[e];
      z[kt][e + 4] = bf2f(v[e + 4]) + r1[e];
    }
#pragma unroll
    for (int e = 0; e < 8; ++e) { s += z[kt][e]; ss += z[kt][e] * z[kt][e]; }
  }
  s += __shfl_xor(s, 1, 64);  ss += __shfl_xor(ss, 1, 64);
  s += __shfl_xor(s, 2, 64);  ss += __shfl_xor(ss, 2, 64);
  s += __shfl_xor(s, 4, 64);  ss += __shfl_xor(ss, 4, 64);
  const float mean = s * (1.f / 1024.f);
  const float var = ss * (1.f / 1024.f) - mean * mean;
  const float rstd = rsqrtf(var + 1e-5f);

#pragma unroll
  for (int kt = 0; kt < 16; ++kt) {
    f32x4 g0 = *(const f32x4*)&lng[kt * 64 + gc * 8];
    f32x4 g1 = *(const f32x4*)&lng[kt * 64 + gc * 8 + 4];
    f32x4 b0 = *(const f32x4*)&lnb[kt * 64 + gc * 8];
    f32x4 b1 = *(const f32x4*)&lnb[kt * 64 + gc * 8 + 4];
    f32x4 o0, o1;
#pragma unroll
    for (int e = 0; e < 4; ++e) {
      o0[e] = (z[kt][e] - mean) * rstd * g0[e] + b0[e];
      o1[e] = (z[kt][e + 4] - mean) * rstd * g1[e] + b1[e];
    }
    if (OPK) {
      u16x8 ov;
#pragma unroll
      for (int e = 0; e < 4; ++e) { ov[e] = f2bf(o0[e]); ov[e + 4] = f2bf(o1[e]); }
      *(u16x8*)&opk[((size_t)(tile * NKT + kt) * 128) * 64 + (size_t)gidx * 8] = ov;
    }
    if (OF32) {
      float* op = of32 + grow * D_DIM + kt * 64 + gc * 8;
      *(f32x4*)op = o0;
      *(f32x4*)(op + 4) = o1;
    }
  }
}

// ---------------- f32 row-major -> PK bf16 (block = 128-row tile) ----------
__global__ __launch_bounds__(256) void pack_pk(const float* __restrict__ src,
                                               u16* __restrict__ dst)
{
  const int t_r = blockIdx.x;
#pragma unroll 4
  for (int i = 0; i < 64; ++i) {
    const int idx = i * 256 + threadIdx.x;
    const int r = idx >> 7;            // 0..127
    const int gsf = idx & 127;         // 8-col group within full row
    const float* sp = src + (size_t)(t_r * 128 + r) * D_DIM + gsf * 8;
    f32x4 a = *(const f32x4*)sp;
    f32x4 b = *(const f32x4*)(sp + 4);
    u16x8 o;
#pragma unroll
    for (int t = 0; t < 4; ++t) { o[t] = f2bf(a[t]); o[t + 4] = f2bf(b[t]); }
    const int kt = gsf >> 3, g3 = gsf & 7;
    *(u16x8*)&dst[((size_t)(t_r * NKT + kt) * 128 + r) * 64 + ((g3 ^ (r & 7)) * 8)] = o;
  }
}

struct TP4 { const float* s[4]; u16* d[4]; };

// wv (f32 row-major) -> wv^T as PK bf16, batched z=0..3
__global__ __launch_bounds__(256) void transpose_pack(TP4 p) {
  __shared__ float tile[32][33];
  const int z = blockIdx.z;
  const float* src = p.s[z];
  u16* dst = p.d[z];
  const int tx = threadIdx.x & 31, ty = threadIdx.x >> 5;
  const int gx = blockIdx.x * 32, gy = blockIdx.y * 32;
#pragma unroll
  for (int i = 0; i < 4; ++i) {
    const int r = ty + i * 8;
    tile[r][tx] = src[(size_t)(gy + r) * D_DIM + gx + tx];
  }
  __syncthreads();
#pragma unroll
  for (int i = 0; i < 4; ++i) {
    const int drow = gx + ty + i * 8;
    const int dcol = gy + tx;
    const int t_n = drow >> 7, rr = drow & 127;
    const int kt = dcol >> 6, gs = (dcol >> 3) & 7, e = dcol & 7;
    dst[((size_t)(t_n * NKT + kt) * 128 + rr) * 64 + ((gs ^ (rr & 7)) * 8) + e] =
        f2bf(tile[tx][ty + i * 8]);
  }
}

struct BiasArgs { const float* wout[4]; const float* bin[4]; const float* bout[4]; };

__global__ __launch_bounds__(256) void bias_kernel(BiasArgs p, float* cb) {
  const int z = blockIdx.z;
  const int i = blockIdx.x * 256 + threadIdx.x;
  const float* wrow = p.wout[z] + (size_t)i * D_DIM;
  const float* bv = p.bin[z] + 2 * D_DIM;
  float s = 0.f;
  for (int j = 0; j < D_DIM; j += 4) {
    f32x4 w4 = *(const f32x4*)&wrow[j];
    f32x4 b4 = *(const f32x4*)&bv[j];
#pragma unroll
    for (int t = 0; t < 4; ++t) s += w4[t] * b4[t];
  }
  cb[(size_t)z * D_DIM + i] = s + p.bout[z][i];
}

extern "C" void kernel_launch(void* const* d_in, const int* in_sizes, int n_in,
                              void* d_out, int out_size, void* d_ws, size_t ws_size,
                              hipStream_t stream) {
  (void)in_sizes; (void)n_in; (void)out_size; (void)ws_size;
  const size_t BD = (size_t)B_ROWS * D_DIM;
  const size_t DD = (size_t)D_DIM * D_DIM;

  const float* feat_local = (const float*)d_in[0];
  const float* feat_tact  = (const float*)d_in[1];
  const float* feat_strat = (const float*)d_in[2];
  const float* w_in[4]  = {(const float*)d_in[3],  (const float*)d_in[7],  (const float*)d_in[11], (const float*)d_in[15]};
  const float* b_in[4]  = {(const float*)d_in[4],  (const float*)d_in[8],  (const float*)d_in[12], (const float*)d_in[16]};
  const float* w_out[4] = {(const float*)d_in[5],  (const float*)d_in[9],  (const float*)d_in[13], (const float*)d_in[17]};
  const float* b_out[4] = {(const float*)d_in[6],  (const float*)d_in[10], (const float*)d_in[14], (const float*)d_in[18]};
  const float* ln_g[3] = {(const float*)d_in[19], (const float*)d_in[21], (const float*)d_in[23]};
  const float* ln_b[3] = {(const float*)d_in[20], (const float*)d_in[22], (const float*)d_in[24]};

  u16* pkA = (u16*)d_ws;               // local_pk -> strat_pk (128 MB)
  u16* pkY = pkA + BD;                 // y per stage (128 MB)
  u16* pkB = pkY + BD;                 // tacA_pk -> tacB_pk (128 MB)
  float* tacF = (float*)(pkB + BD);    // tacA f32 row-major (256 MB)
  u16* wvT  = (u16*)(tacF + BD);       // 4*DD PK
  u16* wobf = wvT + 4 * DD;            // 4*DD PK
  u16* Wc   = wobf + 4 * DD;           // 4*DD PK
  float* cb = (float*)(Wc + 4 * DD);

  float* out = (float*)d_out;
  float* o_loc = out;
  float* o_tac = out + BD;
  float* o_str = out + 2 * BD;

  // 0. pack: local f32 -> PK (pkA); w_out -> PK
  hipLaunchKernelGGL(pack_pk, dim3(512), dim3(256), 0, stream, feat_local, pkA);
  for (int z = 0; z < 4; ++z)
    hipLaunchKernelGGL(pack_pk, dim3(8), dim3(256), 0, stream, w_out[z], wobf + z * DD);

  // 1. wvT_z = (w_in_z[2D:,:])^T as PK
  TP4 tp;
  for (int z = 0; z < 4; ++z) { tp.s[z] = w_in[z] + 2 * DD; tp.d[z] = wvT + z * DD; }
  hipLaunchKernelGGL(transpose_pack, dim3(32, 32, 4), dim3(256), 0, stream, tp);

  // 2. combined bias c = w_out*bv + b_out (f32)
  BiasArgs ba;
  for (int z = 0; z < 4; ++z) { ba.wout[z] = w_out[z]; ba.bin[z] = b_in[z]; ba.bout[z] = b_out[z]; }
  hipLaunchKernelGGL(bias_kernel, dim3(4, 1, 4), dim3(256), 0, stream, ba, cb);

  // 3. Wc_z = wobf_z @ wvT_z^T -> PK
  for (int z = 0; z < 4; ++z)
    hipLaunchKernelGGL((gemm_pk<0, 2>), dim3(8, 8), dim3(256), 0, stream,
                       wobf + z * DD, wvT + z * DD, (const float*)nullptr,
                       (const float*)nullptr, (void*)(Wc + z * DD));

  // 4. S1: y1 = local_pk @ Wc0 + c0 -> pkY ; LN1(y1 + tact) -> pkB (tacA) + tacF
  hipLaunchKernelGGL((gemm_pk<0, 2>), dim3(8, 512), dim3(256), 0, stream,
                     pkA, Wc + 0 * DD, cb + 0, (const float*)nullptr, (void*)pkY);
  hipLaunchKernelGGL((ln_pk<1, 1>), dim3(512, 4), dim3(256), 0, stream,
                     pkY, feat_tact, ln_g[0], ln_b[0], tacF, pkB);

  // 5. S2: y2 = tacA_pk @ Wc1 + c1 -> pkY ; LN2(y2 + strat) -> o_str f32 + pkA (strat_pk)
  hipLaunchKernelGGL((gemm_pk<0, 2>), dim3(8, 512), dim3(256), 0, stream,
                     pkB, Wc + 1 * DD, cb + 1024, (const float*)nullptr, (void*)pkY);
  hipLaunchKernelGGL((ln_pk<1, 1>), dim3(512, 4), dim3(256), 0, stream,
                     pkY, feat_strat, ln_g[1], ln_b[1], o_str, pkA);

  // 6. S3: y3 = strat_pk @ Wc2 + c2 -> pkY ; LN3(y3 + tacA_f32) -> o_tac f32 + pkB (tacB)
  hipLaunchKernelGGL((gemm_pk<0, 2>), dim3(8, 512), dim3(256), 0, stream,
                     pkA, Wc + 2 * DD, cb + 2048, (const float*)nullptr, (void*)pkY);
  hipLaunchKernelGGL((ln_pk<1, 1>), dim3(512, 4), dim3(256), 0, stream,
                     pkY, tacF, ln_g[2], ln_b[2], o_tac, pkB);

  // 7. S4: loc = local(f32) + tacB_pk @ Wc3 + c3 -> o_loc f32 (no LN)
  hipLaunchKernelGGL((gemm_pk<1, 1>), dim3(8, 512), dim3(256), 0, stream,
                     pkB, Wc + 3 * DD, cb + 3072, feat_local, (void*)o_loc);
}

// Round 15
// 1326.970 us; speedup vs baseline: 1.4162x; 1.1170x over previous
//
#include <hip/hip_runtime.h>

#define D_DIM 1024
#define B_ROWS 65536
#define NKT 16                 // K tiles of 64 (K = 1024 everywhere)
#define TILE_U16 8192          // 128 rows x 64 cols bf16

typedef unsigned short u16;
typedef __attribute__((ext_vector_type(8))) __bf16 bf16x8;
typedef __attribute__((ext_vector_type(4))) float f32x4;
typedef __attribute__((ext_vector_type(8))) unsigned short u16x8;

typedef const __attribute__((address_space(1))) void* gas_cptr;
typedef __attribute__((address_space(3))) void* las_ptr;

__device__ __forceinline__ u16 f2bf(float f) {
  union { float fv; unsigned int i; } v; v.fv = f;
  return (u16)((v.i + 0x7FFFu + ((v.i >> 16) & 1u)) >> 16);
}
__device__ __forceinline__ float bf2f(u16 u) {
  union { unsigned int i; float f; } v; v.i = ((unsigned int)u) << 16; return v.f;
}

// ---------------------------------------------------------------------------
// PK layout (tile-major): P(t,kt,r,g) = ((t*NKT+kt)*128 + r)*64 + g*8 (u16),
// t=row>>7, r=row&127, kt=col>>6; granule g holds cols kt*64 + (g^(r&7))*8.
// Each (t,kt) chunk = 16 KB contiguous -> perfect HBM streams.
// ---------------------------------------------------------------------------

// ---------------- GEMM: C = A_pk @ W_pk^T (+bias) (+R) ----------------------
// 128x128 tile, BK=64, 4 waves, glds of CONTIGUOUS 16 KB packed tiles,
// LDS-staged coalesced epilogue. RESID: 0 none, 1 f32 row-major, 2 PK bf16.
// OUTM: 1 f32 row-major, 2 PK bf16.  zs: per-blockIdx.z offset (u16 elems).
template <int RESID, int OUTM>
__global__ __launch_bounds__(256, 4) void gemm_pk(
    const u16* __restrict__ Ap, const u16* __restrict__ Wp,
    const float* __restrict__ bias, const void* Rp, void* Op, size_t zs)
{
  __shared__ __align__(16) u16 smem[2 * TILE_U16];   // 32 KB: sA | sB, reused as eC
  u16* sA = smem;
  u16* sB = smem + TILE_U16;

  const size_t zoff = (size_t)blockIdx.z * zs;
  const int bm = blockIdx.y, bn = blockIdx.x;
  const int tid = threadIdx.x;
  const int wave = tid >> 6;
  const int lane = tid & 63;
  const int wm = wave >> 1, wn = wave & 1;
  const int fr = lane & 15;
  const int l4 = lane >> 4;

  const u16* Abase = Ap + zoff + (size_t)bm * NKT * TILE_U16;
  const u16* Wbase = Wp + zoff + (size_t)bn * NKT * TILE_U16;

  f32x4 acc[4][4] = {};

  for (int kt = 0; kt < NKT; ++kt) {
    const u16* at = Abase + kt * TILE_U16;
    const u16* wt = Wbase + kt * TILE_U16;
#pragma unroll
    for (int i = 0; i < 4; ++i) {
      __builtin_amdgcn_global_load_lds((gas_cptr)(at + (i * 256 + tid) * 8),
                                       (las_ptr)(sA + (i * 256 + tid) * 8), 16, 0, 0);
      __builtin_amdgcn_global_load_lds((gas_cptr)(wt + (i * 256 + tid) * 8),
                                       (las_ptr)(sB + (i * 256 + tid) * 8), 16, 0, 0);
    }
    __syncthreads();
#pragma unroll
    for (int ks = 0; ks < 2; ++ks) {
      bf16x8 af[4], bf[4];
#pragma unroll
      for (int m = 0; m < 4; ++m) {
        const int row = wm * 64 + m * 16 + fr;
        af[m] = *(const bf16x8*)&sA[row * 64 + (((ks * 4 + l4) ^ (row & 7)) * 8)];
      }
#pragma unroll
      for (int n = 0; n < 4; ++n) {
        const int row = wn * 64 + n * 16 + fr;
        bf[n] = *(const bf16x8*)&sB[row * 64 + (((ks * 4 + l4) ^ (row & 7)) * 8)];
      }
#pragma unroll
      for (int m = 0; m < 4; ++m)
#pragma unroll
        for (int n = 0; n < 4; ++n)
          acc[m][n] = __builtin_amdgcn_mfma_f32_16x16x32_bf16(af[m], bf[n], acc[m][n], 0, 0, 0);
    }
    __syncthreads();
  }

  // -------- LDS-staged epilogue: two half-tiles of 64 rows --------
  float* eC = (float*)smem;            // 64 x 128 f32, c4-XOR anti-bank
  const float* Rf = (const float*)Rp;
  const u16*   Rb = (const u16*)Rp;
  const int q4 = l4 * 4;
#pragma unroll
  for (int H = 0; H < 2; ++H) {
    if (wm == H) {
#pragma unroll
      for (int m = 0; m < 4; ++m)
#pragma unroll
        for (int j = 0; j < 4; ++j) {
          const int r = m * 16 + q4 + j;
#pragma unroll
          for (int n = 0; n < 4; ++n) {
            const int c = wn * 64 + n * 16 + fr;
            const int c4 = c >> 2;
            eC[r * 128 + ((c4 ^ ((r >> 2) & 7)) * 4) + (c & 3)] = acc[m][n][j];
          }
        }
    }
    __syncthreads();
#pragma unroll
    for (int it = 0; it < 4; ++it) {
      const int idx = it * 256 + tid;
      const int r = idx >> 4;          // 0..63
      const int g8 = idx & 15;         // 8-col group within 128
      const int gr = bm * 128 + H * 64 + r;
      const int c4a = g8 * 2, c4b = g8 * 2 + 1;
      const int rx = (r >> 2) & 7;
      f32x4 c0 = *(const f32x4*)&eC[r * 128 + ((c4a ^ rx) * 4)];
      f32x4 c1 = *(const f32x4*)&eC[r * 128 + ((c4b ^ rx) * 4)];
      const int gc0 = bn * 128 + g8 * 8;
      if (bias) {
        f32x4 b0 = *(const f32x4*)&bias[gc0];
        f32x4 b1 = *(const f32x4*)&bias[gc0 + 4];
#pragma unroll
        for (int t = 0; t < 4; ++t) { c0[t] += b0[t]; c1[t] += b1[t]; }
      }
      if (RESID == 1) {
        const float* rp = Rf + (size_t)gr * D_DIM + gc0;
        f32x4 r0 = *(const f32x4*)rp;
        f32x4 r1 = *(const f32x4*)(rp + 4);
#pragma unroll
        for (int t = 0; t < 4; ++t) { c0[t] += r0[t]; c1[t] += r1[t]; }
      }
      if (RESID == 2) {
        const int t_r = gr >> 7, rr = gr & 127;
        const int kt = gc0 >> 6, gs = (gc0 & 63) >> 3;
        const size_t P = ((size_t)(t_r * NKT + kt) * 128 + rr) * 64 + ((gs ^ (rr & 7)) * 8);
        u16x8 rv = *(const u16x8*)&Rb[P];
#pragma unroll
        for (int t = 0; t < 4; ++t) { c0[t] += bf2f(rv[t]); c1[t] += bf2f(rv[t + 4]); }
      }
      if (OUTM == 1) {
        float* op = (float*)Op + (size_t)gr * D_DIM + gc0;
        *(f32x4*)op = c0;
        *(f32x4*)(op + 4) = c1;
      } else {
        const int t_r = gr >> 7, rr = gr & 127;
        const int kt = gc0 >> 6, gs = (gc0 & 63) >> 3;
        const size_t P = ((size_t)(t_r * NKT + kt) * 128 + rr) * 64 + ((gs ^ (rr & 7)) * 8);
        u16x8 ov;
#pragma unroll
        for (int t = 0; t < 4; ++t) { ov[t] = f2bf(c0[t]); ov[t + 4] = f2bf(c1[t]); }
        *(u16x8*)&((u16*)Op + zoff)[P] = ov;
      }
    }
    __syncthreads();
  }
}

// ---------------- LayerNorm over PK: y already has bias+residual -----------
// Thread = one granule column (128 cols of one row, z[16][8] static).
// All PK accesses are 4 KB contiguous chunk streams. Row reduce = 3 shfl_xor.
template <int OF32, int OPK>
__global__ __launch_bounds__(256, 2) void ln_pk(
    const u16* __restrict__ Yp,
    const float* __restrict__ lng, const float* __restrict__ lnb,
    float* __restrict__ of32, u16* __restrict__ opk)
{
  const int tile = blockIdx.x;                     // 128-row tile
  const int gidx = blockIdx.y * 256 + threadIdx.x; // granule within chunk
  const int r = gidx >> 3;                         // row within tile
  const int g = gidx & 7;
  const int gc = g ^ (r & 7);                      // logical col-group
  const size_t grow = (size_t)tile * 128 + r;

  float z[16][8];
  float s = 0.f, ss = 0.f;
#pragma unroll
  for (int kt = 0; kt < 16; ++kt) {
    u16x8 v = *(const u16x8*)&Yp[((size_t)(tile * NKT + kt) * 128) * 64 + (size_t)gidx * 8];
#pragma unroll
    for (int e = 0; e < 8; ++e) {
      z[kt][e] = bf2f(v[e]);
      s += z[kt][e]; ss += z[kt][e] * z[kt][e];
    }
  }
  s += __shfl_xor(s, 1, 64);  ss += __shfl_xor(ss, 1, 64);
  s += __shfl_xor(s, 2, 64);  ss += __shfl_xor(ss, 2, 64);
  s += __shfl_xor(s, 4, 64);  ss += __shfl_xor(ss, 4, 64);
  const float mean = s * (1.f / 1024.f);
  const float var = ss * (1.f / 1024.f) - mean * mean;
  const float rstd = rsqrtf(var + 1e-5f);

#pragma unroll
  for (int kt = 0; kt < 16; ++kt) {
    f32x4 g0 = *(const f32x4*)&lng[kt * 64 + gc * 8];
    f32x4 g1 = *(const f32x4*)&lng[kt * 64 + gc * 8 + 4];
    f32x4 b0 = *(const f32x4*)&lnb[kt * 64 + gc * 8];
    f32x4 b1 = *(const f32x4*)&lnb[kt * 64 + gc * 8 + 4];
    f32x4 o0, o1;
#pragma unroll
    for (int e = 0; e < 4; ++e) {
      o0[e] = (z[kt][e] - mean) * rstd * g0[e] + b0[e];
      o1[e] = (z[kt][e + 4] - mean) * rstd * g1[e] + b1[e];
    }
    if (OPK) {
      u16x8 ov;
#pragma unroll
      for (int e = 0; e < 4; ++e) { ov[e] = f2bf(o0[e]); ov[e + 4] = f2bf(o1[e]); }
      *(u16x8*)&opk[((size_t)(tile * NKT + kt) * 128) * 64 + (size_t)gidx * 8] = ov;
    }
    if (OF32) {
      float* op = of32 + grow * D_DIM + kt * 64 + gc * 8;
      *(f32x4*)op = o0;
      *(f32x4*)(op + 4) = o1;
    }
  }
}

// ---------------- f32 row-major -> PK bf16 (block = 128-row tile) ----------
__global__ __launch_bounds__(256) void pack_pk(const float* __restrict__ src,
                                               u16* __restrict__ dst)
{
  const int t_r = blockIdx.x;
#pragma unroll 4
  for (int i = 0; i < 64; ++i) {
    const int idx = i * 256 + threadIdx.x;
    const int r = idx >> 7;            // 0..127
    const int gsf = idx & 127;         // 8-col group within full row
    const float* sp = src + (size_t)(t_r * 128 + r) * D_DIM + gsf * 8;
    f32x4 a = *(const f32x4*)sp;
    f32x4 b = *(const f32x4*)(sp + 4);
    u16x8 o;
#pragma unroll
    for (int t = 0; t < 4; ++t) { o[t] = f2bf(a[t]); o[t + 4] = f2bf(b[t]); }
    const int kt = gsf >> 3, g3 = gsf & 7;
    *(u16x8*)&dst[((size_t)(t_r * NKT + kt) * 128 + r) * 64 + ((g3 ^ (r & 7)) * 8)] = o;
  }
}

struct PW4 { const float* s[4]; u16* d[4]; };

// batched w_out packs: grid (8, 4)
__global__ __launch_bounds__(256) void pack_w4(PW4 p) {
  const int t_r = blockIdx.x;
  const int z = blockIdx.y;
  const float* src = p.s[z];
  u16* dst = p.d[z];
#pragma unroll 4
  for (int i = 0; i < 64; ++i) {
    const int idx = i * 256 + threadIdx.x;
    const int r = idx >> 7;
    const int gsf = idx & 127;
    const float* sp = src + (size_t)(t_r * 128 + r) * D_DIM + gsf * 8;
    f32x4 a = *(const f32x4*)sp;
    f32x4 b = *(const f32x4*)(sp + 4);
    u16x8 o;
#pragma unroll
    for (int t = 0; t < 4; ++t) { o[t] = f2bf(a[t]); o[t + 4] = f2bf(b[t]); }
    const int kt = gsf >> 3, g3 = gsf & 7;
    *(u16x8*)&dst[((size_t)(t_r * NKT + kt) * 128 + r) * 64 + ((g3 ^ (r & 7)) * 8)] = o;
  }
}

struct TP4 { const float* s[4]; u16* d[4]; };

// wv (f32 row-major) -> wv^T as PK bf16, batched z=0..3
__global__ __launch_bounds__(256) void transpose_pack(TP4 p) {
  __shared__ float tile[32][33];
  const int z = blockIdx.z;
  const float* src = p.s[z];
  u16* dst = p.d[z];
  const int tx = threadIdx.x & 31, ty = threadIdx.x >> 5;
  const int gx = blockIdx.x * 32, gy = blockIdx.y * 32;
#pragma unroll
  for (int i = 0; i < 4; ++i) {
    const int r = ty + i * 8;
    tile[r][tx] = src[(size_t)(gy + r) * D_DIM + gx + tx];
  }
  __syncthreads();
#pragma unroll
  for (int i = 0; i < 4; ++i) {
    const int drow = gx + ty + i * 8;
    const int dcol = gy + tx;
    const int t_n = drow >> 7, rr = drow & 127;
    const int kt = dcol >> 6, gs = (dcol >> 3) & 7, e = dcol & 7;
    dst[((size_t)(t_n * NKT + kt) * 128 + rr) * 64 + ((gs ^ (rr & 7)) * 8) + e] =
        f2bf(tile[tx][ty + i * 8]);
  }
}

struct BiasArgs { const float* wout[4]; const float* bin[4]; const float* bout[4]; };

__global__ __launch_bounds__(256) void bias_kernel(BiasArgs p, float* cb) {
  const int z = blockIdx.z;
  const int i = blockIdx.x * 256 + threadIdx.x;
  const float* wrow = p.wout[z] + (size_t)i * D_DIM;
  const float* bv = p.bin[z] + 2 * D_DIM;
  float s = 0.f;
  for (int j = 0; j < D_DIM; j += 4) {
    f32x4 w4 = *(const f32x4*)&wrow[j];
    f32x4 b4 = *(const f32x4*)&bv[j];
#pragma unroll
    for (int t = 0; t < 4; ++t) s += w4[t] * b4[t];
  }
  cb[(size_t)z * D_DIM + i] = s + p.bout[z][i];
}

extern "C" void kernel_launch(void* const* d_in, const int* in_sizes, int n_in,
                              void* d_out, int out_size, void* d_ws, size_t ws_size,
                              hipStream_t stream) {
  (void)in_sizes; (void)n_in; (void)out_size; (void)ws_size;
  const size_t BD = (size_t)B_ROWS * D_DIM;
  const size_t DD = (size_t)D_DIM * D_DIM;

  const float* feat_local = (const float*)d_in[0];
  const float* feat_tact  = (const float*)d_in[1];
  const float* feat_strat = (const float*)d_in[2];
  const float* w_in[4]  = {(const float*)d_in[3],  (const float*)d_in[7],  (const float*)d_in[11], (const float*)d_in[15]};
  const float* b_in[4]  = {(const float*)d_in[4],  (const float*)d_in[8],  (const float*)d_in[12], (const float*)d_in[16]};
  const float* w_out[4] = {(const float*)d_in[5],  (const float*)d_in[9],  (const float*)d_in[13], (const float*)d_in[17]};
  const float* b_out[4] = {(const float*)d_in[6],  (const float*)d_in[10], (const float*)d_in[14], (const float*)d_in[18]};
  const float* ln_g[3] = {(const float*)d_in[19], (const float*)d_in[21], (const float*)d_in[23]};
  const float* ln_b[3] = {(const float*)d_in[20], (const float*)d_in[22], (const float*)d_in[24]};

  u16* pkA = (u16*)d_ws;               // local_pk -> strat_pk (128 MB)
  u16* pkY = pkA + BD;                 // y per stage (128 MB)
  u16* pkB = pkY + BD;                 // tacA_pk -> tacB_pk (128 MB)
  u16* wvT  = pkB + BD;                // 4*DD PK
  u16* wobf = wvT + 4 * DD;            // 4*DD PK
  u16* Wc   = wobf + 4 * DD;           // 4*DD PK
  float* cb = (float*)(Wc + 4 * DD);

  float* out = (float*)d_out;
  float* o_loc = out;
  float* o_tac = out + BD;
  float* o_str = out + 2 * BD;

  // 0. pack: local f32 -> PK (pkA); w_out x4 -> PK (one launch)
  hipLaunchKernelGGL(pack_pk, dim3(512), dim3(256), 0, stream, feat_local, pkA);
  PW4 pw;
  for (int z = 0; z < 4; ++z) { pw.s[z] = w_out[z]; pw.d[z] = wobf + z * DD; }
  hipLaunchKernelGGL(pack_w4, dim3(8, 4), dim3(256), 0, stream, pw);

  // 1. wvT_z = (w_in_z[2D:,:])^T as PK
  TP4 tp;
  for (int z = 0; z < 4; ++z) { tp.s[z] = w_in[z] + 2 * DD; tp.d[z] = wvT + z * DD; }
  hipLaunchKernelGGL(transpose_pack, dim3(32, 32, 4), dim3(256), 0, stream, tp);

  // 2. combined bias c = w_out*bv + b_out (f32)
  BiasArgs ba;
  for (int z = 0; z < 4; ++z) { ba.wout[z] = w_out[z]; ba.bin[z] = b_in[z]; ba.bout[z] = b_out[z]; }
  hipLaunchKernelGGL(bias_kernel, dim3(4, 1, 4), dim3(256), 0, stream, ba, cb);

  // 3. Wc_z = wobf_z @ wvT_z^T -> PK (one launch, grid.z = 4, zstride = DD)
  hipLaunchKernelGGL((gemm_pk<0, 2>), dim3(8, 8, 4), dim3(256), 0, stream,
                     wobf, wvT, (const float*)nullptr, (const void*)nullptr,
                     (void*)Wc, DD);

  // 4. S1: y1 = local_pk@Wc0 + c0 + tact -> pkY ; LN1 -> pkB (tacA, PK only)
  hipLaunchKernelGGL((gemm_pk<1, 2>), dim3(8, 512, 1), dim3(256), 0, stream,
                     pkA, Wc + 0 * DD, cb + 0, (const void*)feat_tact, (void*)pkY, 0);
  hipLaunchKernelGGL((ln_pk<0, 1>), dim3(512, 4), dim3(256), 0, stream,
                     pkY, ln_g[0], ln_b[0], (float*)nullptr, pkB);

  // 5. S2: y2 = tacA@Wc1 + c1 + strat -> pkY ; LN2 -> o_str f32 + pkA (strat_pk)
  hipLaunchKernelGGL((gemm_pk<1, 2>), dim3(8, 512, 1), dim3(256), 0, stream,
                     pkB, Wc + 1 * DD, cb + 1024, (const void*)feat_strat, (void*)pkY, 0);
  hipLaunchKernelGGL((ln_pk<1, 1>), dim3(512, 4), dim3(256), 0, stream,
                     pkY, ln_g[1], ln_b[1], o_str, pkA);

  // 6. S3: y3 = strat@Wc2 + c2 + tacA(PK) -> pkY ; LN3 -> o_tac f32 + pkB (tacB)
  hipLaunchKernelGGL((gemm_pk<2, 2>), dim3(8, 512, 1), dim3(256), 0, stream,
                     pkA, Wc + 2 * DD, cb + 2048, (const void*)pkB, (void*)pkY, 0);
  hipLaunchKernelGGL((ln_pk<1, 1>), dim3(512, 4), dim3(256), 0, stream,
                     pkY, ln_g[2], ln_b[2], o_tac, pkB);

  // 7. S4: loc = local + tacB@Wc3 + c3 -> o_loc f32 (no LN)
  hipLaunchKernelGGL((gemm_pk<1, 1>), dim3(8, 512, 1), dim3(256), 0, stream,
                     pkB, Wc + 3 * DD, cb + 3072, (const void*)feat_local, (void*)o_loc, 0);
}